// Round 11
// baseline (286.822 us; speedup 1.0000x reference)
//
#include <hip/hip_runtime.h>
#include <stdint.h>

#define CIN 64
#define HHW 112
#define NPIX 12544
#define COUT 128
#define KTOT 576      // 9 offsets * 64 cin
#define NBUCKETS 16

typedef __attribute__((ext_vector_type(8))) short s8v;            // 8 x bf16
typedef __attribute__((ext_vector_type(4))) short s4v;            // 4 x bf16
typedef __attribute__((ext_vector_type(4))) float f4v;            // 4 x f32
typedef __attribute__((ext_vector_type(8))) unsigned short u8v;

__device__ __forceinline__ unsigned short f2bf(float f) {
  unsigned int u = __float_as_uint(f);
  unsigned int r = (u + 0x7fffu + ((u >> 16) & 1u)) >> 16;   // RNE
  return (unsigned short)r;
}

__device__ __forceinline__ void gload_lds16(const void* g, void* l) {
  __builtin_amdgcn_global_load_lds(
      (const __attribute__((address_space(1))) unsigned int*)g,
      (__attribute__((address_space(3))) unsigned int*)l, 16, 0, 0);
}

// ---- prep: min/max, sequential bucket cascade, bf16 convert, K-reorder ----
// W2 layout: [hf][co][off*64+cin] bf16  (rows 0..255 = hf*128+co, stride KTOT)
__global__ __launch_bounds__(1024) void hashedconv_prep_kernel(
    const float* __restrict__ W, const float* __restrict__ hashed_w,
    unsigned short* __restrict__ W2, unsigned short* __restrict__ zp) {
  const int NW = COUT * CIN * 9;
  int tid = threadIdx.x;
  if (zp && tid < 128) zp[tid] = 0;
  float vmin = 1e30f, vmax = -1e30f;
  for (int i = tid; i < NW; i += 1024) {
    float v = W[i];
    vmin = fminf(vmin, v);
    vmax = fmaxf(vmax, v);
  }
  #pragma unroll
  for (int off = 32; off > 0; off >>= 1) {
    vmin = fminf(vmin, __shfl_down(vmin, off, 64));
    vmax = fmaxf(vmax, __shfl_down(vmax, off, 64));
  }
  __shared__ float smin[16], smax[16];
  __shared__ float s_wmin, s_step;
  __shared__ float hv[NBUCKETS];
  int wave = tid >> 6, lane = tid & 63;
  if (lane == 0) { smin[wave] = vmin; smax[wave] = vmax; }
  if (tid < NBUCKETS) hv[tid] = hashed_w[tid];
  __syncthreads();
  if (tid == 0) {
    float m = smin[0], M = smax[0];
    #pragma unroll
    for (int i = 1; i < 16; ++i) { m = fminf(m, smin[i]); M = fmaxf(M, smax[i]); }
    s_wmin = m;
    s_step = (M - m) / (float)NBUCKETS;
  }
  __syncthreads();
  float wmin = s_wmin, step = s_step;
  for (int i = tid; i < NW; i += 1024) {
    float v = W[i];
    int co  = i / 576;
    int rem = i - co * 576;
    int cin = rem / 9;
    int off = rem - cin * 9;
    float h = v;
    #pragma unroll
    for (int bb = 0; bb < NBUCKETS; ++bb) {
      float thr = (float)(bb + 1) * step + wmin;
      if (h > thr) h = hv[bb];
    }
    int oidx = co * KTOT + off * 64 + cin;
    W2[oidx]               = f2bf(v);
    W2[COUT * KTOT + oidx] = f2bf(h);
  }
}

// ---- x: NCHW f32 -> NHWC bf16, vectorized (float4 loads) ----
__global__ __launch_bounds__(256) void xpose_kernel(
    const float* __restrict__ x, unsigned short* __restrict__ xb) {
  __shared__ unsigned short t2[64][260];
  const int n = blockIdx.y, p0 = blockIdx.x * 256, tid = threadIdx.x;
  const int q = tid & 63;
  const int c0 = (tid >> 6) * 16;
  const int p4 = q * 4;
  const float* xp = x + (size_t)n * CIN * NPIX + p0 + p4;
  #pragma unroll
  for (int cc = 0; cc < 16; ++cc) {
    int c = c0 + cc;
    f4v v = *(const f4v*)(xp + (size_t)c * NPIX);
    s4v pk;
    pk[0] = (short)f2bf(v[0]);
    pk[1] = (short)f2bf(v[1]);
    pk[2] = (short)f2bf(v[2]);
    pk[3] = (short)f2bf(v[3]);
    *(s4v*)(&t2[c][p4]) = pk;
  }
  __syncthreads();
  unsigned short* ob = xb + ((size_t)n * NPIX + p0) * 64;
  #pragma unroll
  for (int it = 0; it < 8; ++it) {
    int u = it * 256 + tid;
    int px = u >> 3, slot = u & 7;
    u8v v;
    #pragma unroll
    for (int k = 0; k < 8; ++k) v[k] = t2[slot * 8 + k][px];
    *(u8v*)(ob + (size_t)u * 8) = v;
  }
}

// ---- implicit-GEMM dual conv, BM=256 FUSED (both hf), BN=128 px ----
// 4 waves (2M x 2N), wave tile 128co x 64px: 32 MFMA : 12 ds_read per phase
// (2x the per-barrier MFMA of r8). x staged ONCE for both convs.
// LDS = 22.5 + 3*16 = 70.5KB -> 2 blocks/CU. 18 phases K=32, 3-slot ring,
// counted vmcnt(4) (stage = 4 gloads/thread).
#define XS_SHORTS (180 * 64)             // 11520 shorts = 22.5KB (18x10 halo)
#define HALF2_SHORTS (256 * 32)          // 8192 shorts = 16KB per ring slot

__global__ __launch_bounds__(256, 2) void hashedconv_mfma_kernel(
    const unsigned short* __restrict__ xb, const unsigned short* __restrict__ W2,
    const float* __restrict__ b, const float* __restrict__ b2,
    const unsigned short* __restrict__ zp, float* __restrict__ out,
    size_t out_half) {
  __shared__ __attribute__((aligned(16))) short lds[XS_SHORTS + 3 * HALF2_SHORTS];
  short* xs = lds;
  short* ring = lds + XS_SHORTS;

  const int tid = threadIdx.x;
  const int bx = blockIdx.x;           // 0..97 : 14x7 tiles of 8x16 px
  const int n  = blockIdx.y;
  const int ty = bx / 7, tx = bx - ty * 7;
  const int h0 = ty * 8, w0 = tx * 16;
  const int lane = tid & 63, wv = tid >> 6;
  const int wr = wv >> 1;              // M half: 0 -> hf0 (rows 0..127), 1 -> hf1
  const int wcn = wv & 1;              // N half (64 px)
  const int lrow = lane & 15, g = lane >> 4;

  // ---- prologue: stage x tile (18x10 = 180 px), <=6 gloads/thread ----
  #pragma unroll
  for (int it = 0; it < 6; ++it) {
    int u = it * 256 + tid;            // 1440 16B-units
    if (u < 1440) {
      int pix = u >> 3, slot = u & 7;
      int py = pix / 18, px = pix - py * 18;
      int gh = h0 - 1 + py, gw = w0 - 1 + px;
      bool inb = (gh >= 0) & (gh < HHW) & (gw >= 0) & (gw < HHW);
      int srcslot = slot ^ (pix & 7);
      const unsigned short* gsrc = inb
          ? xb + (((size_t)n * NPIX + gh * HHW + gw) * 64 + srcslot * 8)
          : zp + srcslot * 8;
      gload_lds16(gsrc, xs + (size_t)u * 8 - (size_t)(lane * 8));
    }
  }

  // stage one weight half-chunk (K=32 slice, ALL 256 rows) into ring slot h%3
  auto stage_half = [&](int h) {
    short* buf = ring + (size_t)(h % 3) * HALF2_SHORTS;
    const unsigned short* src = W2 + (h >> 1) * 64 + (h & 1) * 32;
    #pragma unroll
    for (int j = 0; j < 4; ++j) {
      int u = j * 256 + tid;           // 1024 16B-units: [256 rows][4 slots]
      int row = u >> 2, slot = u & 3;
      int srcs = slot ^ ((row >> 2) & 3);
      gload_lds16(src + (size_t)row * KTOT + srcs * 8,
                  buf + (size_t)(j * 256 + wv * 64) * 8);
    }
  };
  stage_half(0);
  stage_half(1);

  f4v acc[8][4];
  #pragma unroll
  for (int i = 0; i < 8; ++i)
    #pragma unroll
    for (int j = 0; j < 4; ++j) acc[i][j] = (f4v)(0.f);

  int sbase[4];                        // pixel LDS row base per nt
  #pragma unroll
  for (int nt = 0; nt < 4; ++nt) {
    int p = wcn * 64 + nt * 16 + lrow;
    sbase[nt] = (p >> 4) * 18 + (p & 15);
  }

#define PHASE(h_, VM)                                                        \
  {                                                                          \
    asm volatile("s_waitcnt vmcnt(" #VM ")" ::: "memory");                   \
    __builtin_amdgcn_s_barrier();                                            \
    const int h = (h_);                                                      \
    if (h + 2 <= 17) stage_half(h + 2);                                      \
    const short* wbuf = ring + (size_t)(h % 3) * HALF2_SHORTS;               \
    const int ch = h >> 1;                                                   \
    const int dh = ch / 3, dw = ch - dh * 3;                                 \
    const int kofs = (h & 1) * 32 + g * 8;                                   \
    s8v af[8], bfv[4];                                                       \
    _Pragma("unroll") for (int mt = 0; mt < 8; ++mt) {                       \
      int row = wr * 128 + mt * 16 + lrow;                                   \
      af[mt] = *(const s8v*)(wbuf + row * 32 + (g ^ ((row >> 2) & 3)) * 8);  \
    }                                                                        \
    _Pragma("unroll") for (int nt = 0; nt < 4; ++nt) {                       \
      int s = sbase[nt] + dh * 18 + dw;                                      \
      bfv[nt] = *(const s8v*)(xs + s * 64 + (kofs ^ ((s & 7) << 3)));        \
    }                                                                        \
    asm volatile("s_waitcnt lgkmcnt(0)" ::: "memory");                       \
    __builtin_amdgcn_sched_barrier(0);                                       \
    __builtin_amdgcn_s_setprio(1);                                           \
    _Pragma("unroll") for (int mt = 0; mt < 8; ++mt)                         \
      _Pragma("unroll") for (int nt = 0; nt < 4; ++nt)                       \
        acc[mt][nt] = __builtin_amdgcn_mfma_f32_16x16x32_bf16(               \
            af[mt], bfv[nt], acc[mt][nt], 0, 0, 0);                          \
    __builtin_amdgcn_s_setprio(0);                                           \
    __builtin_amdgcn_sched_barrier(0);                                       \
  }

  for (int c = 0; c < 8; ++c) {
    PHASE(2 * c, 4);
    PHASE(2 * c + 1, 4);
  }
  PHASE(16, 4);
  PHASE(17, 0);
#undef PHASE

  // ---- epilogue: bias + store (hf == wr, wave-uniform) ----
  const float* bias = wr ? b2 : b;
  float* obase = out + (size_t)wr * out_half + (size_t)n * COUT * NPIX;
  #pragma unroll
  for (int mt = 0; mt < 8; ++mt) {
    #pragma unroll
    for (int r = 0; r < 4; ++r) {
      int co = mt * 16 + g * 4 + r;    // 0..127 within this half
      float bv = bias[co];
      #pragma unroll
      for (int nt = 0; nt < 4; ++nt) {
        int p = wcn * 64 + nt * 16 + lrow;
        int h = h0 + (p >> 4), w = w0 + (p & 15);
        obase[(size_t)co * NPIX + h * HHW + w] = acc[mt][nt][r] + bv;
      }
    }
  }
}

// ---- fallback (reg-staged from fp32 x) if ws too small ----
__global__ __launch_bounds__(256) void hashedconv_fb_kernel(
    const float* __restrict__ x, const unsigned short* __restrict__ W2,
    const float* __restrict__ b, const float* __restrict__ b2,
    float* __restrict__ out, size_t out_half) {
  __shared__ __attribute__((aligned(16))) short lds[11520 + 8192];
  short* xs = lds;
  short* wcs = lds + 11520;
  const int tid = threadIdx.x;
  const int bx = blockIdx.x;
  const int n  = blockIdx.y;
  const int hf = blockIdx.z;
  const int ty = bx / 7, tx = bx - ty * 7;
  const int h0 = ty * 8, w0 = tx * 16;
  const int lane = tid & 63, wv = tid >> 6;
  const int wr = wv >> 1, wcn = wv & 1;
  const int lrow = lane & 15, g = lane >> 4;
  f4v acc[4][4];
  #pragma unroll
  for (int i = 0; i < 4; ++i)
    #pragma unroll
    for (int j = 0; j < 4; ++j) acc[i][j] = (f4v)(0.f);
  const float* xn = x + (size_t)n * CIN * NPIX;
  for (int u = tid; u < 1440; u += 256) {
    int cg = u / 180;
    int pix = u - cg * 180;
    int pyp = pix / 18, pxp = pix - pyp * 18;
    int gh = h0 - 1 + pyp, gw = w0 - 1 + pxp;
    bool inb = (gh >= 0) & (gh < HHW) & (gw >= 0) & (gw < HHW);
    const float* xp = xn + (size_t)(cg * 8) * NPIX + gh * HHW + gw;
    s8v pk;
    #pragma unroll
    for (int cc = 0; cc < 8; ++cc) {
      float v = inb ? xp[(size_t)cc * NPIX] : 0.f;
      pk[cc] = (short)f2bf(v);
    }
    *(s8v*)(xs + pix * 64 + ((cg * 8) ^ ((pix & 7) << 3))) = pk;
  }
  const unsigned short* Wh = W2 + (size_t)hf * COUT * KTOT;
  for (int c = 0; c < 9; ++c) {
    #pragma unroll
    for (int j = 0; j < 4; ++j) {
      int u = tid + j * 256;
      int row = u >> 3, slot = u & 7;
      s8v v = *(const s8v*)(Wh + (size_t)row * KTOT + c * 64 + slot * 8);
      *(s8v*)(wcs + row * 64 + ((slot * 8) ^ ((row & 7) << 3))) = v;
    }
    __syncthreads();
    int dh = c / 3, dw = c - dh * 3;
    #pragma unroll
    for (int kh2 = 0; kh2 < 2; ++kh2) {
      int kofs = kh2 * 32 + g * 8;
      s8v af[4], bfv[4];
      #pragma unroll
      for (int mt = 0; mt < 4; ++mt) {
        int row = wr * 64 + mt * 16 + lrow;
        af[mt] = *(const s8v*)(wcs + row * 64 + (kofs ^ ((row & 7) << 3)));
      }
      #pragma unroll
      for (int nt = 0; nt < 4; ++nt) {
        int p = wcn * 64 + nt * 16 + lrow;
        int s = ((p >> 4) + dh) * 18 + ((p & 15) + dw);
        bfv[nt] = *(const s8v*)(xs + s * 64 + (kofs ^ ((s & 7) << 3)));
      }
      #pragma unroll
      for (int mt = 0; mt < 4; ++mt)
        #pragma unroll
        for (int nt = 0; nt < 4; ++nt)
          acc[mt][nt] = __builtin_amdgcn_mfma_f32_16x16x32_bf16(
              af[mt], bfv[nt], acc[mt][nt], 0, 0, 0);
    }
    __syncthreads();
  }
  const float* bias = hf ? b2 : b;
  float* obase = out + (size_t)hf * out_half + (size_t)n * COUT * NPIX;
  #pragma unroll
  for (int mt = 0; mt < 4; ++mt) {
    #pragma unroll
    for (int r = 0; r < 4; ++r) {
      int co = wr * 64 + mt * 16 + g * 4 + r;
      float bv = bias[co];
      #pragma unroll
      for (int nt = 0; nt < 4; ++nt) {
        int p = wcn * 64 + nt * 16 + lrow;
        int h = h0 + (p >> 4), w = w0 + (p & 15);
        obase[(size_t)co * NPIX + h * HHW + w] = acc[mt][nt][r] + bv;
      }
    }
  }
}

extern "C" void kernel_launch(void* const* d_in, const int* in_sizes, int n_in,
                              void* d_out, int out_size, void* d_ws, size_t ws_size,
                              hipStream_t stream) {
  const float* x      = (const float*)d_in[0];
  const float* W      = (const float*)d_in[1];
  const float* b      = (const float*)d_in[2];
  const float* b2     = (const float*)d_in[3];
  const float* hashed = (const float*)d_in[4];
  float* out = (float*)d_out;

  const int N = in_sizes[0] / (CIN * NPIX);
  const size_t out_half = (size_t)N * COUT * NPIX;
  const size_t XB_SHORTS = (size_t)N * NPIX * 64;
  const size_t need = (XB_SHORTS + 2 * COUT * KTOT) * 2 + 256;

  if (ws_size >= need) {
    unsigned short* xb = (unsigned short*)d_ws;
    unsigned short* W2 = xb + XB_SHORTS;
    unsigned short* zp = W2 + 2 * COUT * KTOT;
    hipLaunchKernelGGL(hashedconv_prep_kernel, dim3(1), dim3(1024), 0, stream,
                       W, hashed, W2, zp);
    hipLaunchKernelGGL(xpose_kernel, dim3(NPIX / 256, N), dim3(256), 0, stream,
                       x, xb);
    hipLaunchKernelGGL(hashedconv_mfma_kernel, dim3(98, N), dim3(256), 0,
                       stream, xb, W2, b, b2, zp, out, out_half);
  } else {
    unsigned short* W2 = (unsigned short*)d_ws;
    hipLaunchKernelGGL(hashedconv_prep_kernel, dim3(1), dim3(1024), 0, stream,
                       W, hashed, W2, (unsigned short*)nullptr);
    hipLaunchKernelGGL(hashedconv_fb_kernel, dim3(98, N, 2), dim3(256), 0,
                       stream, x, W2, b, b2, out, out_half);
  }
}

// Round 12
// 260.196 us; speedup vs baseline: 1.1023x; 1.1023x over previous
//
#include <hip/hip_runtime.h>
#include <stdint.h>

#define CIN 64
#define HHW 112
#define NPIX 12544
#define COUT 128
#define KTOT 576      // 9 offsets * 64 cin
#define NBUCKETS 16

typedef __attribute__((ext_vector_type(8))) short s8v;            // 8 x bf16
typedef __attribute__((ext_vector_type(4))) float f4v;            // 4 x f32
typedef __attribute__((ext_vector_type(8))) unsigned short u8v;

__device__ __forceinline__ unsigned short f2bf(float f) {
  unsigned int u = __float_as_uint(f);
  unsigned int r = (u + 0x7fffu + ((u >> 16) & 1u)) >> 16;   // RNE
  return (unsigned short)r;
}

__device__ __forceinline__ void gload_lds16(const void* g, void* l) {
  __builtin_amdgcn_global_load_lds(
      (const __attribute__((address_space(1))) unsigned int*)g,
      (__attribute__((address_space(3))) unsigned int*)l, 16, 0, 0);
}

// ---- prep: min/max, sequential bucket cascade, bf16 convert, K-reorder ----
// W2 layout: [hf][co][off*64+cin] bf16
__global__ __launch_bounds__(1024) void hashedconv_prep_kernel(
    const float* __restrict__ W, const float* __restrict__ hashed_w,
    unsigned short* __restrict__ W2, unsigned short* __restrict__ zp) {
  const int NW = COUT * CIN * 9;
  int tid = threadIdx.x;
  if (zp && tid < 128) zp[tid] = 0;
  float vmin = 1e30f, vmax = -1e30f;
  for (int i = tid; i < NW; i += 1024) {
    float v = W[i];
    vmin = fminf(vmin, v);
    vmax = fmaxf(vmax, v);
  }
  #pragma unroll
  for (int off = 32; off > 0; off >>= 1) {
    vmin = fminf(vmin, __shfl_down(vmin, off, 64));
    vmax = fmaxf(vmax, __shfl_down(vmax, off, 64));
  }
  __shared__ float smin[16], smax[16];
  __shared__ float s_wmin, s_step;
  __shared__ float hv[NBUCKETS];
  int wave = tid >> 6, lane = tid & 63;
  if (lane == 0) { smin[wave] = vmin; smax[wave] = vmax; }
  if (tid < NBUCKETS) hv[tid] = hashed_w[tid];
  __syncthreads();
  if (tid == 0) {
    float m = smin[0], M = smax[0];
    #pragma unroll
    for (int i = 1; i < 16; ++i) { m = fminf(m, smin[i]); M = fmaxf(M, smax[i]); }
    s_wmin = m;
    s_step = (M - m) / (float)NBUCKETS;
  }
  __syncthreads();
  float wmin = s_wmin, step = s_step;
  for (int i = tid; i < NW; i += 1024) {
    float v = W[i];
    int co  = i / 576;
    int rem = i - co * 576;
    int cin = rem / 9;
    int off = rem - cin * 9;
    float h = v;
    #pragma unroll
    for (int bb = 0; bb < NBUCKETS; ++bb) {
      float thr = (float)(bb + 1) * step + wmin;
      if (h > thr) h = hv[bb];
    }
    int oidx = co * KTOT + off * 64 + cin;
    W2[oidx]               = f2bf(v);
    W2[COUT * KTOT + oidx] = f2bf(h);
  }
}

// ---- x: NCHW f32 -> NHWC bf16 (r8's proven version) ----
__global__ __launch_bounds__(256) void xpose_kernel(
    const float* __restrict__ x, unsigned short* __restrict__ xb) {
  __shared__ unsigned short t[64][264];
  const int n = blockIdx.y, p0 = blockIdx.x * 256, tid = threadIdx.x;
  const float* xp = x + (size_t)n * CIN * NPIX + p0;
  #pragma unroll
  for (int c = 0; c < 64; ++c)
    t[c][tid] = f2bf(xp[(size_t)c * NPIX + tid]);
  __syncthreads();
  unsigned short* ob = xb + ((size_t)n * NPIX + p0) * 64;
  #pragma unroll
  for (int it = 0; it < 8; ++it) {
    int u = it * 256 + tid;            // 2048 16B-units
    int px = u >> 3, slot = u & 7;
    u8v v;
    #pragma unroll
    for (int k = 0; k < 8; ++k) v[k] = t[slot * 8 + k][px];
    *(u8v*)(ob + (size_t)u * 8) = v;
  }
}

// ---- implicit-GEMM dual conv (r8 structure; phase body reordered) ----
// BM=128 (hf via blockIdx.z), BN=128 px (16x8), 4 waves, 3 blocks/CU.
// 18 phases K=32; 3-slot ring, counted vmcnt(2).
// r12 changes vs r8: ds_reads FIRST in phase (critical path), stage issue
// second, no setprio, minimal sched_barriers (keep rule-18 fence only).
#define XS_SHORTS (180 * 64)             // 11520 shorts = 22.5KB (18x10 halo)
#define HALF_SHORTS (128 * 32)           // 4096 shorts = 8KB per ring slot

__global__ __launch_bounds__(256, 3) void hashedconv_mfma_kernel(
    const unsigned short* __restrict__ xb, const unsigned short* __restrict__ W2,
    const float* __restrict__ b, const float* __restrict__ b2,
    const unsigned short* __restrict__ zp, float* __restrict__ out,
    size_t out_half) {
  __shared__ __attribute__((aligned(16))) short lds[XS_SHORTS + 3 * HALF_SHORTS];
  short* xs = lds;
  short* ring = lds + XS_SHORTS;

  const int tid = threadIdx.x;
  const int bx = blockIdx.x;           // 0..97 : 14x7 tiles of 8x16 px
  const int n  = blockIdx.y;
  const int hf = blockIdx.z;
  const int ty = bx / 7, tx = bx - ty * 7;
  const int h0 = ty * 8, w0 = tx * 16;
  const int lane = tid & 63, wv = tid >> 6;
  const int wr = wv >> 1;              // M half (64 co)
  const int wcn = wv & 1;              // N half (64 px)
  const int lrow = lane & 15, g = lane >> 4;

  const unsigned short* Wh = W2 + (size_t)hf * COUT * KTOT;

  // ---- prologue: stage x tile (18x10 = 180 px), <=6 gloads/thread ----
  #pragma unroll
  for (int it = 0; it < 6; ++it) {
    int u = it * 256 + tid;            // 1440 16B-units
    if (u < 1440) {
      int pix = u >> 3, slot = u & 7;
      int py = pix / 18, px = pix - py * 18;
      int gh = h0 - 1 + py, gw = w0 - 1 + px;
      bool inb = (gh >= 0) & (gh < HHW) & (gw >= 0) & (gw < HHW);
      int srcslot = slot ^ (pix & 7);
      const unsigned short* gsrc = inb
          ? xb + (((size_t)n * NPIX + gh * HHW + gw) * 64 + srcslot * 8)
          : zp + srcslot * 8;
      gload_lds16(gsrc, xs + (size_t)u * 8 - (size_t)(lane * 8));
    }
  }

  // stage one weight half-chunk (K=32 slice) into ring slot h%3
  auto stage_half = [&](int h) {
    short* buf = ring + (size_t)(h % 3) * HALF_SHORTS;
    const unsigned short* src = Wh + (h >> 1) * 64 + (h & 1) * 32;
    #pragma unroll
    for (int j = 0; j < 2; ++j) {
      int u = j * 256 + tid;           // 512 16B-units: [128 rows][4 slots]
      int row = u >> 2, slot = u & 3;
      int srcs = slot ^ ((row >> 2) & 3);
      gload_lds16(src + (size_t)row * KTOT + srcs * 8,
                  buf + (size_t)(j * 256 + wv * 64) * 8);
    }
  };
  stage_half(0);
  stage_half(1);

  f4v acc[4][4];
  #pragma unroll
  for (int i = 0; i < 4; ++i)
    #pragma unroll
    for (int j = 0; j < 4; ++j) acc[i][j] = (f4v)(0.f);

  int sbase[4];                        // pixel LDS row base per nt
  #pragma unroll
  for (int nt = 0; nt < 4; ++nt) {
    int p = wcn * 64 + nt * 16 + lrow;
    sbase[nt] = (p >> 4) * 18 + (p & 15);
  }

#define PHASE(h_, VM)                                                        \
  {                                                                          \
    asm volatile("s_waitcnt vmcnt(" #VM ")" ::: "memory");                   \
    __builtin_amdgcn_s_barrier();                                            \
    const int h = (h_);                                                      \
    const short* wbuf = ring + (size_t)(h % 3) * HALF_SHORTS;                \
    const int ch = h >> 1;                                                   \
    const int dh = ch / 3, dw = ch - dh * 3;                                 \
    const int kofs = (h & 1) * 32 + g * 8;                                   \
    s8v af[4], bfv[4];                                                       \
    _Pragma("unroll") for (int mt = 0; mt < 4; ++mt) {                       \
      int row = wr * 64 + mt * 16 + lrow;                                    \
      af[mt] = *(const s8v*)(wbuf + row * 32 + (g ^ ((row >> 2) & 3)) * 8);  \
    }                                                                        \
    _Pragma("unroll") for (int nt = 0; nt < 4; ++nt) {                       \
      int s = sbase[nt] + dh * 18 + dw;                                      \
      bfv[nt] = *(const s8v*)(xs + s * 64 + (kofs ^ ((s & 7) << 3)));        \
    }                                                                        \
    if (h + 2 <= 17) stage_half(h + 2);                                      \
    asm volatile("s_waitcnt lgkmcnt(0)" ::: "memory");                       \
    __builtin_amdgcn_sched_barrier(0);  /* rule-18 fence: MFMA not hoisted */ \
    _Pragma("unroll") for (int mt = 0; mt < 4; ++mt)                         \
      _Pragma("unroll") for (int nt = 0; nt < 4; ++nt)                       \
        acc[mt][nt] = __builtin_amdgcn_mfma_f32_16x16x32_bf16(               \
            af[mt], bfv[nt], acc[mt][nt], 0, 0, 0);                          \
  }

  for (int c = 0; c < 8; ++c) {
    PHASE(2 * c, 2);
    PHASE(2 * c + 1, 2);
  }
  PHASE(16, 2);
  PHASE(17, 0);
#undef PHASE

  // ---- epilogue: bias + store ----
  const float* bias = hf ? b2 : b;
  float* obase = out + (size_t)hf * out_half + (size_t)n * COUT * NPIX;
  #pragma unroll
  for (int mt = 0; mt < 4; ++mt) {
    #pragma unroll
    for (int r = 0; r < 4; ++r) {
      int co = wr * 64 + mt * 16 + g * 4 + r;
      float bv = bias[co];
      #pragma unroll
      for (int nt = 0; nt < 4; ++nt) {
        int p = wcn * 64 + nt * 16 + lrow;
        int h = h0 + (p >> 4), w = w0 + (p & 15);
        obase[(size_t)co * NPIX + h * HHW + w] = acc[mt][nt][r] + bv;
      }
    }
  }
}

// ---- fallback (reg-staged from fp32 x) if ws too small ----
__global__ __launch_bounds__(256) void hashedconv_fb_kernel(
    const float* __restrict__ x, const unsigned short* __restrict__ W2,
    const float* __restrict__ b, const float* __restrict__ b2,
    float* __restrict__ out, size_t out_half) {
  __shared__ __attribute__((aligned(16))) short lds[11520 + 8192];
  short* xs = lds;
  short* wcs = lds + 11520;
  const int tid = threadIdx.x;
  const int bx = blockIdx.x;
  const int n  = blockIdx.y;
  const int hf = blockIdx.z;
  const int ty = bx / 7, tx = bx - ty * 7;
  const int h0 = ty * 8, w0 = tx * 16;
  const int lane = tid & 63, wv = tid >> 6;
  const int wr = wv >> 1, wcn = wv & 1;
  const int lrow = lane & 15, g = lane >> 4;
  f4v acc[4][4];
  #pragma unroll
  for (int i = 0; i < 4; ++i)
    #pragma unroll
    for (int j = 0; j < 4; ++j) acc[i][j] = (f4v)(0.f);
  const float* xn = x + (size_t)n * CIN * NPIX;
  for (int u = tid; u < 1440; u += 256) {
    int cg = u / 180;
    int pix = u - cg * 180;
    int pyp = pix / 18, pxp = pix - pyp * 18;
    int gh = h0 - 1 + pyp, gw = w0 - 1 + pxp;
    bool inb = (gh >= 0) & (gh < HHW) & (gw >= 0) & (gw < HHW);
    const float* xp = xn + (size_t)(cg * 8) * NPIX + gh * HHW + gw;
    s8v pk;
    #pragma unroll
    for (int cc = 0; cc < 8; ++cc) {
      float v = inb ? xp[(size_t)cc * NPIX] : 0.f;
      pk[cc] = (short)f2bf(v);
    }
    *(s8v*)(xs + pix * 64 + ((cg * 8) ^ ((pix & 7) << 3))) = pk;
  }
  const unsigned short* Wh = W2 + (size_t)hf * COUT * KTOT;
  for (int c = 0; c < 9; ++c) {
    #pragma unroll
    for (int j = 0; j < 4; ++j) {
      int u = tid + j * 256;
      int row = u >> 3, slot = u & 7;
      s8v v = *(const s8v*)(Wh + (size_t)row * KTOT + c * 64 + slot * 8);
      *(s8v*)(wcs + row * 64 + ((slot * 8) ^ ((row & 7) << 3))) = v;
    }
    __syncthreads();
    int dh = c / 3, dw = c - dh * 3;
    #pragma unroll
    for (int kh2 = 0; kh2 < 2; ++kh2) {
      int kofs = kh2 * 32 + g * 8;
      s8v af[4], bfv[4];
      #pragma unroll
      for (int mt = 0; mt < 4; ++mt) {
        int row = wr * 64 + mt * 16 + lrow;
        af[mt] = *(const s8v*)(wcs + row * 64 + (kofs ^ ((row & 7) << 3)));
      }
      #pragma unroll
      for (int nt = 0; nt < 4; ++nt) {
        int p = wcn * 64 + nt * 16 + lrow;
        int s = ((p >> 4) + dh) * 18 + ((p & 15) + dw);
        bfv[nt] = *(const s8v*)(xs + s * 64 + (kofs ^ ((s & 7) << 3)));
      }
      #pragma unroll
      for (int mt = 0; mt < 4; ++mt)
        #pragma unroll
        for (int nt = 0; nt < 4; ++nt)
          acc[mt][nt] = __builtin_amdgcn_mfma_f32_16x16x32_bf16(
              af[mt], bfv[nt], acc[mt][nt], 0, 0, 0);
    }
    __syncthreads();
  }
  const float* bias = hf ? b2 : b;
  float* obase = out + (size_t)hf * out_half + (size_t)n * COUT * NPIX;
  #pragma unroll
  for (int mt = 0; mt < 4; ++mt) {
    #pragma unroll
    for (int r = 0; r < 4; ++r) {
      int co = wr * 64 + mt * 16 + g * 4 + r;
      float bv = bias[co];
      #pragma unroll
      for (int nt = 0; nt < 4; ++nt) {
        int p = wcn * 64 + nt * 16 + lrow;
        int h = h0 + (p >> 4), w = w0 + (p & 15);
        obase[(size_t)co * NPIX + h * HHW + w] = acc[mt][nt][r] + bv;
      }
    }
  }
}

extern "C" void kernel_launch(void* const* d_in, const int* in_sizes, int n_in,
                              void* d_out, int out_size, void* d_ws, size_t ws_size,
                              hipStream_t stream) {
  const float* x      = (const float*)d_in[0];
  const float* W      = (const float*)d_in[1];
  const float* b      = (const float*)d_in[2];
  const float* b2     = (const float*)d_in[3];
  const float* hashed = (const float*)d_in[4];
  float* out = (float*)d_out;

  const int N = in_sizes[0] / (CIN * NPIX);
  const size_t out_half = (size_t)N * COUT * NPIX;
  const size_t XB_SHORTS = (size_t)N * NPIX * 64;
  const size_t need = (XB_SHORTS + 2 * COUT * KTOT) * 2 + 256;

  if (ws_size >= need) {
    unsigned short* xb = (unsigned short*)d_ws;
    unsigned short* W2 = xb + XB_SHORTS;
    unsigned short* zp = W2 + 2 * COUT * KTOT;
    hipLaunchKernelGGL(hashedconv_prep_kernel, dim3(1), dim3(1024), 0, stream,
                       W, hashed, W2, zp);
    hipLaunchKernelGGL(xpose_kernel, dim3(NPIX / 256, N), dim3(256), 0, stream,
                       x, xb);
    hipLaunchKernelGGL(hashedconv_mfma_kernel, dim3(98, N, 2), dim3(256), 0,
                       stream, xb, W2, b, b2, zp, out, out_half);
  } else {
    unsigned short* W2 = (unsigned short*)d_ws;
    hipLaunchKernelGGL(hashedconv_prep_kernel, dim3(1), dim3(1024), 0, stream,
                       W, hashed, W2, (unsigned short*)nullptr);
    hipLaunchKernelGGL(hashedconv_fb_kernel, dim3(98, N, 2), dim3(256), 0,
                       stream, x, W2, b, b2, out, out_half);
  }
}